// Round 4
// baseline (1094.923 us; speedup 1.0000x reference)
//
#include <hip/hip_runtime.h>
#include <hip/hip_bf16.h>

#define DEVI __device__ __forceinline__

typedef __bf16 bf16_t;
typedef __bf16 bf16x8 __attribute__((ext_vector_type(8)));
typedef __bf16 bf16x4 __attribute__((ext_vector_type(4)));
typedef float  f32x4  __attribute__((ext_vector_type(4)));

// Problem constants
#define STATE   8192
#define DCOND   128
#define NDIM    2048
#define CSZ     512
#define INV_TAU 20.0f
#define SQRT_STATE 90.50966799187809f

// ---------------------------------------------------------------------------
// Prep kernels: transpose/scale weights into bf16 scratch
// ---------------------------------------------------------------------------

// Wt[n][k] = W[k][n]  (2048x2048)
__global__ void prep_wt(const float* __restrict__ W, bf16_t* __restrict__ Wt) {
    __shared__ float tile[32][33];
    int bx = blockIdx.x, by = blockIdx.y;
    int tx = threadIdx.x, ty = threadIdx.y;
    #pragma unroll
    for (int q = 0; q < 4; ++q) {
        int k = by * 32 + ty + q * 8;
        tile[ty + q * 8][tx] = W[(size_t)k * NDIM + bx * 32 + tx];
    }
    __syncthreads();
    #pragma unroll
    for (int q = 0; q < 4; ++q) {
        int n = bx * 32 + ty + q * 8;
        Wt[(size_t)n * NDIM + by * 32 + tx] = (bf16_t)tile[tx][ty + q * 8];
    }
}

// Cst[d][i] = compress[i][d] * (gamma[i]+1) * sqrt(8192)   (128 x 8192)
__global__ void prep_cs(const float* __restrict__ Cmp, const float* __restrict__ gamma,
                        bf16_t* __restrict__ Cst) {
    __shared__ float tile[32][33];
    int bx = blockIdx.x, by = blockIdx.y;   // bx: d-tile (0..3), by: i-tile (0..255)
    int tx = threadIdx.x, ty = threadIdx.y;
    #pragma unroll
    for (int q = 0; q < 4; ++q) {
        int i = by * 32 + ty + q * 8;
        float g = (gamma[i] + 1.0f) * SQRT_STATE;
        tile[ty + q * 8][tx] = Cmp[(size_t)i * DCOND + bx * 32 + tx] * g;
    }
    __syncthreads();
    #pragma unroll
    for (int q = 0; q < 4; ++q) {
        int d = bx * 32 + ty + q * 8;
        Cst[(size_t)d * STATE + by * 32 + tx] = (bf16_t)tile[tx][ty + q * 8];
    }
}

// TLt[n][d], n in [0,640): concat of pre(64) | align(256) | next(256) | post(64), transposed
__global__ void prep_tl(const float* __restrict__ pre, const float* __restrict__ ali,
                        const float* __restrict__ nxt, const float* __restrict__ pst,
                        bf16_t* __restrict__ TLt) {
    int n = blockIdx.x, d = threadIdx.x;
    const float* src; int col, ncols;
    if (n < 64)       { src = pre; col = n;       ncols = 64;  }
    else if (n < 320) { src = ali; col = n - 64;  ncols = 256; }
    else if (n < 576) { src = nxt; col = n - 320; ncols = 256; }
    else              { src = pst; col = n - 576; ncols = 64;  }
    TLt[n * DCOND + d] = (bf16_t)src[d * ncols + col];
}

// ---------------------------------------------------------------------------
// K1a: per-token L2 norm + cast s -> bf16.  zsc[t] = 1/(max(||s||,1e-12)*tau)
// ---------------------------------------------------------------------------
__global__ __launch_bounds__(256) void norms_cast(const float* __restrict__ s,
                                                  bf16_t* __restrict__ sb,
                                                  float* __restrict__ zsc) {
    int t = blockIdx.x;
    const float* row = s + (size_t)t * STATE;
    bf16_t* orow = sb + (size_t)t * STATE;
    float ss = 0.f;
    #pragma unroll
    for (int it = 0; it < 8; ++it) {
        int idx = (it * 256 + threadIdx.x) * 4;
        f32x4 v = *reinterpret_cast<const f32x4*>(row + idx);
        ss += v[0]*v[0] + v[1]*v[1] + v[2]*v[2] + v[3]*v[3];
        bf16x4 o;
        o[0] = (bf16_t)v[0]; o[1] = (bf16_t)v[1]; o[2] = (bf16_t)v[2]; o[3] = (bf16_t)v[3];
        *reinterpret_cast<bf16x4*>(orow + idx) = o;
    }
    ss += __shfl_xor(ss, 1);  ss += __shfl_xor(ss, 2);  ss += __shfl_xor(ss, 4);
    ss += __shfl_xor(ss, 8);  ss += __shfl_xor(ss, 16); ss += __shfl_xor(ss, 32);
    __shared__ float red[4];
    if ((threadIdx.x & 63) == 0) red[threadIdx.x >> 6] = ss;
    __syncthreads();
    if (threadIdx.x == 0) {
        float nrm = sqrtf(red[0] + red[1] + red[2] + red[3]);
        nrm = fmaxf(nrm, 1e-12f);
        zsc[t] = 1.0f / (nrm * 0.05f);
    }
}

// ---------------------------------------------------------------------------
// Generic bf16 GEMM: C[M][N] = A[M][K] @ Bt[N][K]^T, bf16 in, bf16 out, f32 acc.
// 128x128 tile, 4 waves (each 64x64 = 4x4 MFMA 16x16x32 frags), global_load_lds.
// ---------------------------------------------------------------------------
DEVI void gload_lds16(const bf16_t* g, bf16_t* l) {
    __builtin_amdgcn_global_load_lds(
        (const __attribute__((address_space(1))) unsigned int*)g,
        (__attribute__((address_space(3))) unsigned int*)l, 16, 0, 0);
}

__global__ __launch_bounds__(256) void gemm_bt(const bf16_t* __restrict__ A,
                                               const bf16_t* __restrict__ Bt,
                                               bf16_t* __restrict__ C,
                                               int K, int N) {
    __shared__ __align__(16) bf16_t As[128 * 32];
    __shared__ __align__(16) bf16_t Bs[128 * 32];
    const int tid = threadIdx.x;
    const int w = tid >> 6, lane = tid & 63;
    const int l15 = lane & 15, lg = lane >> 4;
    const int bm = blockIdx.x * 128, bn = blockIdx.y * 128;
    const int wr = w >> 1, wc = w & 1;
    const int srow = (lane >> 2);          // row within 16-row staging chunk
    const int scol = (lane & 3) * 8;       // elem col within 32-elem row

    f32x4 acc[4][4] = {};

    for (int kt = 0; kt < K; kt += 32) {
        __syncthreads();
        #pragma unroll
        for (int q = 0; q < 2; ++q) {
            int chunk = w * 2 + q;
            int r = chunk * 16 + srow;
            gload_lds16(A + (size_t)(bm + r) * K + kt + scol, As + chunk * 512);
            gload_lds16(Bt + (size_t)(bn + r) * K + kt + scol, Bs + chunk * 512);
        }
        __syncthreads();
        bf16x8 af[4], bfr[4];
        #pragma unroll
        for (int mi = 0; mi < 4; ++mi)
            af[mi] = *reinterpret_cast<const bf16x8*>(As + (wr * 64 + mi * 16 + l15) * 32 + lg * 8);
        #pragma unroll
        for (int ni = 0; ni < 4; ++ni)
            bfr[ni] = *reinterpret_cast<const bf16x8*>(Bs + (wc * 64 + ni * 16 + l15) * 32 + lg * 8);
        #pragma unroll
        for (int mi = 0; mi < 4; ++mi)
            #pragma unroll
            for (int ni = 0; ni < 4; ++ni)
                acc[mi][ni] = __builtin_amdgcn_mfma_f32_16x16x32_bf16(af[mi], bfr[ni], acc[mi][ni], 0, 0, 0);
    }

    #pragma unroll
    for (int mi = 0; mi < 4; ++mi)
        #pragma unroll
        for (int ni = 0; ni < 4; ++ni)
            #pragma unroll
            for (int r = 0; r < 4; ++r) {
                int row = bm + wr * 64 + mi * 16 + lg * 4 + r;
                int col = bn + wc * 64 + ni * 16 + l15;
                C[(size_t)row * N + col] = (bf16_t)acc[mi][ni][r];
            }
}

// ---------------------------------------------------------------------------
// K2: wave-per-token Sinkhorn on all 4 couplings + fold H_next@H_align, H_next@H_post
// Hs layout per token: [0..63] H_pre (4x16, flat) | [64..319] HA (16x16) | [320..383] HP (16x4)
// ---------------------------------------------------------------------------
DEVI void sink16(const float Z[4], float H[4]) {
    const float lm = -2.7725887222397811f;  // -log(16)
    float u[4], v = 0.f;
    for (int it = 0; it < 20; ++it) {
        #pragma unroll
        for (int k = 0; k < 4; ++k) {
            float x = Z[k] + v;
            float m = x;
            m = fmaxf(m, __shfl_xor(m, 1)); m = fmaxf(m, __shfl_xor(m, 2));
            m = fmaxf(m, __shfl_xor(m, 4)); m = fmaxf(m, __shfl_xor(m, 8));
            float e = __expf(x - m);
            e += __shfl_xor(e, 1); e += __shfl_xor(e, 2);
            e += __shfl_xor(e, 4); e += __shfl_xor(e, 8);
            u[k] = lm - (m + __logf(e));
        }
        float x0 = Z[0] + u[0], x1 = Z[1] + u[1], x2 = Z[2] + u[2], x3 = Z[3] + u[3];
        float m = fmaxf(fmaxf(x0, x1), fmaxf(x2, x3));
        m = fmaxf(m, __shfl_xor(m, 16)); m = fmaxf(m, __shfl_xor(m, 32));
        float e = __expf(x0 - m) + __expf(x1 - m) + __expf(x2 - m) + __expf(x3 - m);
        e += __shfl_xor(e, 16); e += __shfl_xor(e, 32);
        v = lm - (m + __logf(e));
    }
    #pragma unroll
    for (int k = 0; k < 4; ++k) H[k] = __expf(Z[k] + u[k] + v) * 16.0f;
}

__global__ __launch_bounds__(256) void sinkhorn_k(
    const bf16_t* __restrict__ LR, const float* __restrict__ zsc,
    const float* __restrict__ b_pre, const float* __restrict__ b_ali,
    const float* __restrict__ b_nxt, const float* __restrict__ b_pst,
    const float* __restrict__ a_pre, const float* __restrict__ a_ali,
    const float* __restrict__ a_nxt, const float* __restrict__ a_pst,
    float* __restrict__ Hs) {
    const int w = threadIdx.x >> 6, lane = threadIdx.x & 63;
    const int lg = lane >> 4, l15 = lane & 15;
    const int t = blockIdx.x * 4 + w;
    const float zs = zsc[t];
    const bf16_t* lr = LR + (size_t)t * 640;

    __shared__ float sA[4][16][16];
    __shared__ float sN[4][16][16];
    __shared__ float sP[4][16][4];

    // ---- pre: 4x16, lane: r=lane>>4, c=lane&15, n=16
    float Hpre;
    {
        const float sc = a_pre[0] * zs;
        float Z = sc * (float)lr[lane] + b_pre[lane] * INV_TAU;
        const float lm = -2.7725887222397811f;
        float u = 0.f, v = 0.f;
        for (int it = 0; it < 20; ++it) {
            float x = Z + v, m = x;
            m = fmaxf(m, __shfl_xor(m, 1)); m = fmaxf(m, __shfl_xor(m, 2));
            m = fmaxf(m, __shfl_xor(m, 4)); m = fmaxf(m, __shfl_xor(m, 8));
            float e = __expf(x - m);
            e += __shfl_xor(e, 1); e += __shfl_xor(e, 2);
            e += __shfl_xor(e, 4); e += __shfl_xor(e, 8);
            u = lm - (m + __logf(e));
            x = Z + u; m = x;
            m = fmaxf(m, __shfl_xor(m, 16)); m = fmaxf(m, __shfl_xor(m, 32));
            e = __expf(x - m);
            e += __shfl_xor(e, 16); e += __shfl_xor(e, 32);
            v = lm - (m + __logf(e));
        }
        Hpre = __expf(Z + u + v) * 16.0f;
    }

    // ---- align & next: 16x16, lane: c=l15, rows 4*lg+k
    float Hal[4], Hnx[4];
    {
        const float sc = a_ali[0] * zs;
        float Z[4];
        #pragma unroll
        for (int k = 0; k < 4; ++k) {
            int idx = (4 * lg + k) * 16 + l15;
            Z[k] = sc * (float)lr[64 + idx] + b_ali[idx] * INV_TAU;
        }
        sink16(Z, Hal);
    }
    {
        const float sc = a_nxt[0] * zs;
        float Z[4];
        #pragma unroll
        for (int k = 0; k < 4; ++k) {
            int idx = (4 * lg + k) * 16 + l15;
            Z[k] = sc * (float)lr[320 + idx] + b_nxt[idx] * INV_TAU;
        }
        sink16(Z, Hnx);
    }

    // ---- post: 16x4, lane: r=lane>>2, c=lane&3, n=4
    float Hpst;
    {
        const float sc = a_pst[0] * zs;
        float Z = sc * (float)lr[576 + lane] + b_pst[lane] * INV_TAU;
        const float lm = -1.3862943611198906f;  // -log(4)
        float u = 0.f, v = 0.f;
        for (int it = 0; it < 20; ++it) {
            float x = Z + v, m = x;
            m = fmaxf(m, __shfl_xor(m, 1)); m = fmaxf(m, __shfl_xor(m, 2));
            float e = __expf(x - m);
            e += __shfl_xor(e, 1); e += __shfl_xor(e, 2);
            u = lm - (m + __logf(e));
            x = Z + u; m = x;
            m = fmaxf(m, __shfl_xor(m, 4));  m = fmaxf(m, __shfl_xor(m, 8));
            m = fmaxf(m, __shfl_xor(m, 16)); m = fmaxf(m, __shfl_xor(m, 32));
            e = __expf(x - m);
            e += __shfl_xor(e, 4);  e += __shfl_xor(e, 8);
            e += __shfl_xor(e, 16); e += __shfl_xor(e, 32);
            v = lm - (m + __logf(e));
        }
        Hpst = __expf(Z + u + v) * 4.0f;
    }

    // stash to LDS, fold HA = Hnx@Hal, HP = Hnx@Hpst
    #pragma unroll
    for (int k = 0; k < 4; ++k) {
        sA[w][4 * lg + k][l15] = Hal[k];
        sN[w][4 * lg + k][l15] = Hnx[k];
    }
    sP[w][lane >> 2][lane & 3] = Hpst;
    __syncthreads();

    float* ho = Hs + (size_t)t * 384;
    ho[lane] = Hpre;
    #pragma unroll
    for (int k = 0; k < 4; ++k) {
        int r = 4 * lg + k;
        float acc = 0.f;
        #pragma unroll
        for (int j = 0; j < 16; ++j) acc += sN[w][r][j] * sA[w][j][l15];
        ho[64 + r * 16 + l15] = acc;
    }
    {
        int r = lane >> 2, c = lane & 3;
        float acc = 0.f;
        #pragma unroll
        for (int j = 0; j < 16; ++j) acc += sN[w][r][j] * sP[w][j][c];
        ho[320 + lane] = acc;
    }
}

// ---------------------------------------------------------------------------
// K3: layer_in[t] (4x512) = H_pre (4x16) @ s_flat (16x512), bf16 out
// ---------------------------------------------------------------------------
__global__ __launch_bounds__(256) void apply_pre(const bf16_t* __restrict__ sb,
                                                 const float* __restrict__ Hs,
                                                 bf16_t* __restrict__ Lin) {
    int t = blockIdx.x;
    __shared__ float Hp[64];
    if (threadIdx.x < 64) Hp[threadIdx.x] = Hs[(size_t)t * 384 + threadIdx.x];
    __syncthreads();
    int i  = threadIdx.x >> 6;
    int c0 = (threadIdx.x & 63) * 8;
    const bf16_t* srow = sb + (size_t)t * STATE;
    float acc[8] = {};
    #pragma unroll
    for (int j = 0; j < 16; ++j) {
        float h = Hp[i * 16 + j];
        bf16x8 v = *reinterpret_cast<const bf16x8*>(srow + j * CSZ + c0);
        #pragma unroll
        for (int x = 0; x < 8; ++x) acc[x] += h * (float)v[x];
    }
    bf16x8 o;
    #pragma unroll
    for (int x = 0; x < 8; ++x) o[x] = (bf16_t)acc[x];
    *reinterpret_cast<bf16x8*>(Lin + (size_t)t * NDIM + i * CSZ + c0) = o;
}

// ---------------------------------------------------------------------------
// K5: out[t] (16x512) = HA (16x16) @ s_flat + HP (16x4) @ layer_out_flat (4x512)
// ---------------------------------------------------------------------------
__global__ __launch_bounds__(256) void write_out(const bf16_t* __restrict__ sb,
                                                 const bf16_t* __restrict__ Lout,
                                                 const float* __restrict__ Hs,
                                                 float* __restrict__ out) {
    int t = blockIdx.x;
    __shared__ float HA[256];
    __shared__ float HP[64];
    HA[threadIdx.x] = Hs[(size_t)t * 384 + 64 + threadIdx.x];
    if (threadIdx.x < 64) HP[threadIdx.x] = Hs[(size_t)t * 384 + 320 + threadIdx.x];
    __syncthreads();
    int rg = threadIdx.x >> 6;            // rows rg*4 .. rg*4+3
    int c0 = (threadIdx.x & 63) * 8;
    const bf16_t* srow = sb + (size_t)t * STATE;
    const bf16_t* lrow = Lout + (size_t)t * NDIM;
    float acc[4][8] = {};
    #pragma unroll
    for (int j = 0; j < 16; ++j) {
        bf16x8 v = *reinterpret_cast<const bf16x8*>(srow + j * CSZ + c0);
        float vf[8];
        #pragma unroll
        for (int x = 0; x < 8; ++x) vf[x] = (float)v[x];
        #pragma unroll
        for (int rr = 0; rr < 4; ++rr) {
            float h = HA[(rg * 4 + rr) * 16 + j];
            #pragma unroll
            for (int x = 0; x < 8; ++x) acc[rr][x] += h * vf[x];
        }
    }
    #pragma unroll
    for (int j = 0; j < 4; ++j) {
        bf16x8 v = *reinterpret_cast<const bf16x8*>(lrow + j * CSZ + c0);
        float vf[8];
        #pragma unroll
        for (int x = 0; x < 8; ++x) vf[x] = (float)v[x];
        #pragma unroll
        for (int rr = 0; rr < 4; ++rr) {
            float h = HP[(rg * 4 + rr) * 4 + j];
            #pragma unroll
            for (int x = 0; x < 8; ++x) acc[rr][x] += h * vf[x];
        }
    }
    #pragma unroll
    for (int rr = 0; rr < 4; ++rr) {
        float* orow = out + (size_t)t * STATE + (rg * 4 + rr) * CSZ + c0;
        f32x4 o0 = {acc[rr][0], acc[rr][1], acc[rr][2], acc[rr][3]};
        f32x4 o1 = {acc[rr][4], acc[rr][5], acc[rr][6], acc[rr][7]};
        *reinterpret_cast<f32x4*>(orow)     = o0;
        *reinterpret_cast<f32x4*>(orow + 4) = o1;
    }
}

// ---------------------------------------------------------------------------
extern "C" void kernel_launch(void* const* d_in, const int* in_sizes, int n_in,
                              void* d_out, int out_size, void* d_ws, size_t ws_size,
                              hipStream_t stream) {
    const float* s     = (const float*)d_in[0];
    const float* gamma = (const float*)d_in[1];
    const float* cmp   = (const float*)d_in[2];
    const float* b_pre = (const float*)d_in[3];
    const float* a_pre = (const float*)d_in[4];
    const float* tlpre = (const float*)d_in[5];
    const float* b_ali = (const float*)d_in[6];
    const float* a_ali = (const float*)d_in[7];
    const float* tlali = (const float*)d_in[8];
    const float* b_nxt = (const float*)d_in[9];
    const float* a_nxt = (const float*)d_in[10];
    const float* tlnxt = (const float*)d_in[11];
    const float* b_pst = (const float*)d_in[12];
    const float* a_pst = (const float*)d_in[13];
    const float* tlpst = (const float*)d_in[14];
    const float* W     = (const float*)d_in[15];
    float* out = (float*)d_out;
    const int T = in_sizes[0] / STATE;   // 8192

    char* ws = (char*)d_ws;
    size_t off = 0;
    auto take = [&](size_t bytes) {
        char* p = ws + off;
        off += (bytes + 255) & ~(size_t)255;
        return p;
    };
    bf16_t* sb   = (bf16_t*)take((size_t)T * STATE * 2);   // 128 MiB
    bf16_t* Cst  = (bf16_t*)take((size_t)DCOND * STATE * 2);
    bf16_t* TLt  = (bf16_t*)take((size_t)640 * DCOND * 2);
    bf16_t* Wt   = (bf16_t*)take((size_t)NDIM * NDIM * 2);
    float*  zsc  = (float*) take((size_t)T * 4);
    bf16_t* code = (bf16_t*)take((size_t)T * DCOND * 2);
    bf16_t* lrg  = (bf16_t*)take((size_t)T * 640 * 2);
    float*  Hsb  = (float*) take((size_t)T * 384 * 4);
    bf16_t* Lin  = (bf16_t*)take((size_t)T * NDIM * 2);
    bf16_t* Lout = (bf16_t*)take((size_t)T * NDIM * 2);

    prep_wt<<<dim3(64, 64), dim3(32, 8), 0, stream>>>(W, Wt);
    prep_cs<<<dim3(4, 256), dim3(32, 8), 0, stream>>>(cmp, gamma, Cst);
    prep_tl<<<dim3(640), dim3(128), 0, stream>>>(tlpre, tlali, tlnxt, tlpst, TLt);
    norms_cast<<<dim3(T), dim3(256), 0, stream>>>(s, sb, zsc);
    // code_raw = s_bf16 @ Cs^T : M=T, N=128, K=8192
    gemm_bt<<<dim3(T / 128, 1), dim3(256), 0, stream>>>(sb, Cst, code, STATE, DCOND);
    // logits_raw = code_raw @ TL^T : M=T, N=640, K=128
    gemm_bt<<<dim3(T / 128, 5), dim3(256), 0, stream>>>(code, TLt, lrg, DCOND, 640);
    sinkhorn_k<<<dim3(T / 4), dim3(256), 0, stream>>>(lrg, zsc, b_pre, b_ali, b_nxt, b_pst,
                                                      a_pre, a_ali, a_nxt, a_pst, Hsb);
    apply_pre<<<dim3(T), dim3(256), 0, stream>>>(sb, Hsb, Lin);
    // layer_out = layer_in @ W : M=T, N=2048, K=2048
    gemm_bt<<<dim3(T / 128, 16), dim3(256), 0, stream>>>(Lin, Wt, Lout, NDIM, NDIM);
    write_out<<<dim3(T), dim3(256), 0, stream>>>(sb, Lout, Hsb, out);
}

// Round 7
// 931.342 us; speedup vs baseline: 1.1756x; 1.1756x over previous
//
#include <hip/hip_runtime.h>
#include <hip/hip_bf16.h>

#define DEVI __device__ __forceinline__

typedef __bf16 bf16_t;
typedef __bf16 bf16x8 __attribute__((ext_vector_type(8)));
typedef __bf16 bf16x4 __attribute__((ext_vector_type(4)));
typedef float  f32x4  __attribute__((ext_vector_type(4)));

// Problem constants
#define STATE   8192
#define DCOND   128
#define NDIM    2048
#define CSZ     512
#define INV_TAU 20.0f
#define SQRT_STATE 90.50966799187809f
#define SK      8        // split-K factor for the code GEMM (K=8192 -> 1024/chunk)

// ---------------------------------------------------------------------------
// Prep kernels: transpose/scale weights into bf16 scratch
// ---------------------------------------------------------------------------

// Wt[n][k] = W[k][n]  (2048x2048)
__global__ void prep_wt(const float* __restrict__ W, bf16_t* __restrict__ Wt) {
    __shared__ float tile[32][33];
    int bx = blockIdx.x, by = blockIdx.y;
    int tx = threadIdx.x, ty = threadIdx.y;
    #pragma unroll
    for (int q = 0; q < 4; ++q) {
        int k = by * 32 + ty + q * 8;
        tile[ty + q * 8][tx] = W[(size_t)k * NDIM + bx * 32 + tx];
    }
    __syncthreads();
    #pragma unroll
    for (int q = 0; q < 4; ++q) {
        int n = bx * 32 + ty + q * 8;
        Wt[(size_t)n * NDIM + by * 32 + tx] = (bf16_t)tile[tx][ty + q * 8];
    }
}

// Cst[d][i] = compress[i][d] * (gamma[i]+1) * sqrt(8192)   (128 x 8192)
__global__ void prep_cs(const float* __restrict__ Cmp, const float* __restrict__ gamma,
                        bf16_t* __restrict__ Cst) {
    __shared__ float tile[32][33];
    int bx = blockIdx.x, by = blockIdx.y;   // bx: d-tile (0..3), by: i-tile (0..255)
    int tx = threadIdx.x, ty = threadIdx.y;
    #pragma unroll
    for (int q = 0; q < 4; ++q) {
        int i = by * 32 + ty + q * 8;
        float g = (gamma[i] + 1.0f) * SQRT_STATE;
        tile[ty + q * 8][tx] = Cmp[(size_t)i * DCOND + bx * 32 + tx] * g;
    }
    __syncthreads();
    #pragma unroll
    for (int q = 0; q < 4; ++q) {
        int d = bx * 32 + ty + q * 8;
        Cst[(size_t)d * STATE + by * 32 + tx] = (bf16_t)tile[tx][ty + q * 8];
    }
}

// TLt[n][d], n in [0,640): concat of pre(64) | align(256) | next(256) | post(64), transposed
__global__ void prep_tl(const float* __restrict__ pre, const float* __restrict__ ali,
                        const float* __restrict__ nxt, const float* __restrict__ pst,
                        bf16_t* __restrict__ TLt) {
    int n = blockIdx.x, d = threadIdx.x;
    const float* src; int col, ncols;
    if (n < 64)       { src = pre; col = n;       ncols = 64;  }
    else if (n < 320) { src = ali; col = n - 64;  ncols = 256; }
    else if (n < 576) { src = nxt; col = n - 320; ncols = 256; }
    else              { src = pst; col = n - 576; ncols = 64;  }
    TLt[n * DCOND + d] = (bf16_t)src[d * ncols + col];
}

// ---------------------------------------------------------------------------
// K1a: per-token L2 norm + cast s -> bf16.  zsc[t] = 1/(max(||s||,1e-12)*tau)
// ---------------------------------------------------------------------------
__global__ __launch_bounds__(256) void norms_cast(const float* __restrict__ s,
                                                  bf16_t* __restrict__ sb,
                                                  float* __restrict__ zsc) {
    int t = blockIdx.x;
    const float* row = s + (size_t)t * STATE;
    bf16_t* orow = sb + (size_t)t * STATE;
    float ss = 0.f;
    #pragma unroll
    for (int it = 0; it < 8; ++it) {
        int idx = (it * 256 + threadIdx.x) * 4;
        f32x4 v = *reinterpret_cast<const f32x4*>(row + idx);
        ss += v[0]*v[0] + v[1]*v[1] + v[2]*v[2] + v[3]*v[3];
        bf16x4 o;
        o[0] = (bf16_t)v[0]; o[1] = (bf16_t)v[1]; o[2] = (bf16_t)v[2]; o[3] = (bf16_t)v[3];
        *reinterpret_cast<bf16x4*>(orow + idx) = o;
    }
    ss += __shfl_xor(ss, 1);  ss += __shfl_xor(ss, 2);  ss += __shfl_xor(ss, 4);
    ss += __shfl_xor(ss, 8);  ss += __shfl_xor(ss, 16); ss += __shfl_xor(ss, 32);
    __shared__ float red[4];
    if ((threadIdx.x & 63) == 0) red[threadIdx.x >> 6] = ss;
    __syncthreads();
    if (threadIdx.x == 0) {
        float nrm = sqrtf(red[0] + red[1] + red[2] + red[3]);
        nrm = fmaxf(nrm, 1e-12f);
        zsc[t] = 1.0f / (nrm * 0.05f);
    }
}

// ---------------------------------------------------------------------------
// Generic bf16 GEMM: C[M][N] = A[M][K] @ Bt[N][K]^T, bf16 in, bf16 out, f32 acc.
// 128x128 tile, 4 waves (each 64x64 = 4x4 MFMA 16x16x32 frags), global_load_lds.
// ---------------------------------------------------------------------------
DEVI void gload_lds16(const bf16_t* g, bf16_t* l) {
    __builtin_amdgcn_global_load_lds(
        (const __attribute__((address_space(1))) unsigned int*)g,
        (__attribute__((address_space(3))) unsigned int*)l, 16, 0, 0);
}

__global__ __launch_bounds__(256) void gemm_bt(const bf16_t* __restrict__ A,
                                               const bf16_t* __restrict__ Bt,
                                               bf16_t* __restrict__ C,
                                               int K, int N) {
    __shared__ __align__(16) bf16_t As[128 * 32];
    __shared__ __align__(16) bf16_t Bs[128 * 32];
    const int tid = threadIdx.x;
    const int w = tid >> 6, lane = tid & 63;
    const int l15 = lane & 15, lg = lane >> 4;
    const int bm = blockIdx.x * 128, bn = blockIdx.y * 128;
    const int wr = w >> 1, wc = w & 1;
    const int srow = (lane >> 2);          // row within 16-row staging chunk
    const int scol = (lane & 3) * 8;       // elem col within 32-elem row

    f32x4 acc[4][4] = {};

    for (int kt = 0; kt < K; kt += 32) {
        __syncthreads();
        #pragma unroll
        for (int q = 0; q < 2; ++q) {
            int chunk = w * 2 + q;
            int r = chunk * 16 + srow;
            gload_lds16(A + (size_t)(bm + r) * K + kt + scol, As + chunk * 512);
            gload_lds16(Bt + (size_t)(bn + r) * K + kt + scol, Bs + chunk * 512);
        }
        __syncthreads();
        bf16x8 af[4], bfr[4];
        #pragma unroll
        for (int mi = 0; mi < 4; ++mi)
            af[mi] = *reinterpret_cast<const bf16x8*>(As + (wr * 64 + mi * 16 + l15) * 32 + lg * 8);
        #pragma unroll
        for (int ni = 0; ni < 4; ++ni)
            bfr[ni] = *reinterpret_cast<const bf16x8*>(Bs + (wc * 64 + ni * 16 + l15) * 32 + lg * 8);
        #pragma unroll
        for (int mi = 0; mi < 4; ++mi)
            #pragma unroll
            for (int ni = 0; ni < 4; ++ni)
                acc[mi][ni] = __builtin_amdgcn_mfma_f32_16x16x32_bf16(af[mi], bfr[ni], acc[mi][ni], 0, 0, 0);
    }

    #pragma unroll
    for (int mi = 0; mi < 4; ++mi)
        #pragma unroll
        for (int ni = 0; ni < 4; ++ni)
            #pragma unroll
            for (int r = 0; r < 4; ++r) {
                int row = bm + wr * 64 + mi * 16 + lg * 4 + r;
                int col = bn + wc * 64 + ni * 16 + l15;
                C[(size_t)row * N + col] = (bf16_t)acc[mi][ni][r];
            }
}

// ---------------------------------------------------------------------------
// Split-K code GEMM: P[ks][M][128] = A[M][kchunk] @ Cst[128][kchunk]^T (f32)
// grid (M/128, SK). K chunk = STATE/SK = 1024.
// ---------------------------------------------------------------------------
__global__ __launch_bounds__(256) void gemm_code_sk(const bf16_t* __restrict__ A,
                                                    const bf16_t* __restrict__ Bt,
                                                    float* __restrict__ P, int T) {
    __shared__ __align__(16) bf16_t As[128 * 32];
    __shared__ __align__(16) bf16_t Bs[128 * 32];
    const int tid = threadIdx.x;
    const int w = tid >> 6, lane = tid & 63;
    const int l15 = lane & 15, lg = lane >> 4;
    const int bm = blockIdx.x * 128;
    const int kt0 = blockIdx.y * (STATE / SK);
    const int wr = w >> 1, wc = w & 1;
    const int srow = (lane >> 2);
    const int scol = (lane & 3) * 8;

    f32x4 acc[4][4] = {};

    for (int kk = 0; kk < STATE / SK; kk += 32) {
        int kt = kt0 + kk;
        __syncthreads();
        #pragma unroll
        for (int q = 0; q < 2; ++q) {
            int chunk = w * 2 + q;
            int r = chunk * 16 + srow;
            gload_lds16(A + (size_t)(bm + r) * STATE + kt + scol, As + chunk * 512);
            gload_lds16(Bt + (size_t)r * STATE + kt + scol, Bs + chunk * 512);
        }
        __syncthreads();
        bf16x8 af[4], bfr[4];
        #pragma unroll
        for (int mi = 0; mi < 4; ++mi)
            af[mi] = *reinterpret_cast<const bf16x8*>(As + (wr * 64 + mi * 16 + l15) * 32 + lg * 8);
        #pragma unroll
        for (int ni = 0; ni < 4; ++ni)
            bfr[ni] = *reinterpret_cast<const bf16x8*>(Bs + (wc * 64 + ni * 16 + l15) * 32 + lg * 8);
        #pragma unroll
        for (int mi = 0; mi < 4; ++mi)
            #pragma unroll
            for (int ni = 0; ni < 4; ++ni)
                acc[mi][ni] = __builtin_amdgcn_mfma_f32_16x16x32_bf16(af[mi], bfr[ni], acc[mi][ni], 0, 0, 0);
    }

    float* slab = P + (size_t)blockIdx.y * T * DCOND;
    #pragma unroll
    for (int mi = 0; mi < 4; ++mi)
        #pragma unroll
        for (int ni = 0; ni < 2; ++ni)     // only cols 0..127 exist (N=128)
            #pragma unroll
            for (int r = 0; r < 4; ++r) {
                int row = bm + wr * 64 + mi * 16 + lg * 4 + r;
                int col = wc * 64 + ni * 16 + l15;
                slab[(size_t)row * DCOND + col] = acc[mi][ni][r];
            }
}

// code[i] = bf16( sum_ks P[ks][i] ), vectorized x4
__global__ __launch_bounds__(256) void reduce_code_sk(const float* __restrict__ P,
                                                      bf16_t* __restrict__ code, int T) {
    size_t i4 = ((size_t)blockIdx.x * 256 + threadIdx.x) * 4;
    const size_t slab = (size_t)T * DCOND;
    f32x4 acc = *reinterpret_cast<const f32x4*>(P + i4);
    #pragma unroll
    for (int ks = 1; ks < SK; ++ks) {
        f32x4 v = *reinterpret_cast<const f32x4*>(P + ks * slab + i4);
        acc[0] += v[0]; acc[1] += v[1]; acc[2] += v[2]; acc[3] += v[3];
    }
    bf16x4 o;
    o[0] = (bf16_t)acc[0]; o[1] = (bf16_t)acc[1]; o[2] = (bf16_t)acc[2]; o[3] = (bf16_t)acc[3];
    *reinterpret_cast<bf16x4*>(code + i4) = o;
}

// ---------------------------------------------------------------------------
// K2: wave-per-token Sinkhorn on all 4 couplings + fold H_next@H_align, H_next@H_post
// Hs layout per token: [0..63] H_pre (4x16, flat) | [64..319] HA (16x16) | [320..383] HP (16x4)
// ---------------------------------------------------------------------------
DEVI void sink16(const float Z[4], float H[4]) {
    const float lm = -2.7725887222397811f;  // -log(16)
    float u[4], v = 0.f;
    for (int it = 0; it < 20; ++it) {
        #pragma unroll
        for (int k = 0; k < 4; ++k) {
            float x = Z[k] + v;
            float m = x;
            m = fmaxf(m, __shfl_xor(m, 1)); m = fmaxf(m, __shfl_xor(m, 2));
            m = fmaxf(m, __shfl_xor(m, 4)); m = fmaxf(m, __shfl_xor(m, 8));
            float e = __expf(x - m);
            e += __shfl_xor(e, 1); e += __shfl_xor(e, 2);
            e += __shfl_xor(e, 4); e += __shfl_xor(e, 8);
            u[k] = lm - (m + __logf(e));
        }
        float x0 = Z[0] + u[0], x1 = Z[1] + u[1], x2 = Z[2] + u[2], x3 = Z[3] + u[3];
        float m = fmaxf(fmaxf(x0, x1), fmaxf(x2, x3));
        m = fmaxf(m, __shfl_xor(m, 16)); m = fmaxf(m, __shfl_xor(m, 32));
        float e = __expf(x0 - m) + __expf(x1 - m) + __expf(x2 - m) + __expf(x3 - m);
        e += __shfl_xor(e, 16); e += __shfl_xor(e, 32);
        v = lm - (m + __logf(e));
    }
    #pragma unroll
    for (int k = 0; k < 4; ++k) H[k] = __expf(Z[k] + u[k] + v) * 16.0f;
}

__global__ __launch_bounds__(256) void sinkhorn_k(
    const bf16_t* __restrict__ LR, const float* __restrict__ zsc,
    const float* __restrict__ b_pre, const float* __restrict__ b_ali,
    const float* __restrict__ b_nxt, const float* __restrict__ b_pst,
    const float* __restrict__ a_pre, const float* __restrict__ a_ali,
    const float* __restrict__ a_nxt, const float* __restrict__ a_pst,
    float* __restrict__ Hs) {
    const int w = threadIdx.x >> 6, lane = threadIdx.x & 63;
    const int lg = lane >> 4, l15 = lane & 15;
    const int t = blockIdx.x * 4 + w;
    const float zs = zsc[t];
    const bf16_t* lr = LR + (size_t)t * 640;

    __shared__ float sA[4][16][16];
    __shared__ float sN[4][16][16];
    __shared__ float sP[4][16][4];

    // ---- pre: 4x16, lane: r=lane>>4, c=lane&15, n=16
    float Hpre;
    {
        const float sc = a_pre[0] * zs;
        float Z = sc * (float)lr[lane] + b_pre[lane] * INV_TAU;
        const float lm = -2.7725887222397811f;
        float u = 0.f, v = 0.f;
        for (int it = 0; it < 20; ++it) {
            float x = Z + v, m = x;
            m = fmaxf(m, __shfl_xor(m, 1)); m = fmaxf(m, __shfl_xor(m, 2));
            m = fmaxf(m, __shfl_xor(m, 4)); m = fmaxf(m, __shfl_xor(m, 8));
            float e = __expf(x - m);
            e += __shfl_xor(e, 1); e += __shfl_xor(e, 2);
            e += __shfl_xor(e, 4); e += __shfl_xor(e, 8);
            u = lm - (m + __logf(e));
            x = Z + u; m = x;
            m = fmaxf(m, __shfl_xor(m, 16)); m = fmaxf(m, __shfl_xor(m, 32));
            e = __expf(x - m);
            e += __shfl_xor(e, 16); e += __shfl_xor(e, 32);
            v = lm - (m + __logf(e));
        }
        Hpre = __expf(Z + u + v) * 16.0f;
    }

    // ---- align & next: 16x16, lane: c=l15, rows 4*lg+k
    float Hal[4], Hnx[4];
    {
        const float sc = a_ali[0] * zs;
        float Z[4];
        #pragma unroll
        for (int k = 0; k < 4; ++k) {
            int idx = (4 * lg + k) * 16 + l15;
            Z[k] = sc * (float)lr[64 + idx] + b_ali[idx] * INV_TAU;
        }
        sink16(Z, Hal);
    }
    {
        const float sc = a_nxt[0] * zs;
        float Z[4];
        #pragma unroll
        for (int k = 0; k < 4; ++k) {
            int idx = (4 * lg + k) * 16 + l15;
            Z[k] = sc * (float)lr[320 + idx] + b_nxt[idx] * INV_TAU;
        }
        sink16(Z, Hnx);
    }

    // ---- post: 16x4, lane: r=lane>>2, c=lane&3, n=4
    float Hpst;
    {
        const float sc = a_pst[0] * zs;
        float Z = sc * (float)lr[576 + lane] + b_pst[lane] * INV_TAU;
        const float lm = -1.3862943611198906f;  // -log(4)
        float u = 0.f, v = 0.f;
        for (int it = 0; it < 20; ++it) {
            float x = Z + v, m = x;
            m = fmaxf(m, __shfl_xor(m, 1)); m = fmaxf(m, __shfl_xor(m, 2));
            float e = __expf(x - m);
            e += __shfl_xor(e, 1); e += __shfl_xor(e, 2);
            u = lm - (m + __logf(e));
            x = Z + u; m = x;
            m = fmaxf(m, __shfl_xor(m, 4));  m = fmaxf(m, __shfl_xor(m, 8));
            m = fmaxf(m, __shfl_xor(m, 16)); m = fmaxf(m, __shfl_xor(m, 32));
            e = __expf(x - m);
            e += __shfl_xor(e, 4);  e += __shfl_xor(e, 8);
            e += __shfl_xor(e, 16); e += __shfl_xor(e, 32);
            v = lm - (m + __logf(e));
        }
        Hpst = __expf(Z + u + v) * 4.0f;
    }

    // stash to LDS, fold HA = Hnx@Hal, HP = Hnx@Hpst
    #pragma unroll
    for (int k = 0; k < 4; ++k) {
        sA[w][4 * lg + k][l15] = Hal[k];
        sN[w][4 * lg + k][l15] = Hnx[k];
    }
    sP[w][lane >> 2][lane & 3] = Hpst;
    __syncthreads();

    float* ho = Hs + (size_t)t * 384;
    ho[lane] = Hpre;
    #pragma unroll
    for (int k = 0; k < 4; ++k) {
        int r = 4 * lg + k;
        float acc = 0.f;
        #pragma unroll
        for (int j = 0; j < 16; ++j) acc += sN[w][r][j] * sA[w][j][l15];
        ho[64 + r * 16 + l15] = acc;
    }
    {
        int r = lane >> 2, c = lane & 3;
        float acc = 0.f;
        #pragma unroll
        for (int j = 0; j < 16; ++j) acc += sN[w][r][j] * sP[w][j][c];
        ho[320 + lane] = acc;
    }
}

// ---------------------------------------------------------------------------
// K3: layer_in[t] (4x512) = H_pre (4x16) @ s_flat (16x512), bf16 out
// ---------------------------------------------------------------------------
__global__ __launch_bounds__(256) void apply_pre(const bf16_t* __restrict__ sb,
                                                 const float* __restrict__ Hs,
                                                 bf16_t* __restrict__ Lin) {
    int t = blockIdx.x;
    __shared__ float Hp[64];
    if (threadIdx.x < 64) Hp[threadIdx.x] = Hs[(size_t)t * 384 + threadIdx.x];
    __syncthreads();
    int i  = threadIdx.x >> 6;
    int c0 = (threadIdx.x & 63) * 8;
    const bf16_t* srow = sb + (size_t)t * STATE;
    float acc[8] = {};
    #pragma unroll
    for (int j = 0; j < 16; ++j) {
        float h = Hp[i * 16 + j];
        bf16x8 v = *reinterpret_cast<const bf16x8*>(srow + j * CSZ + c0);
        #pragma unroll
        for (int x = 0; x < 8; ++x) acc[x] += h * (float)v[x];
    }
    bf16x8 o;
    #pragma unroll
    for (int x = 0; x < 8; ++x) o[x] = (bf16_t)acc[x];
    *reinterpret_cast<bf16x8*>(Lin + (size_t)t * NDIM + i * CSZ + c0) = o;
}

// ---------------------------------------------------------------------------
// K5: out[t] (16x512) = HA (16x16) @ s_flat + HP (16x4) @ layer_out_flat (4x512)
// ---------------------------------------------------------------------------
__global__ __launch_bounds__(256) void write_out(const bf16_t* __restrict__ sb,
                                                 const bf16_t* __restrict__ Lout,
                                                 const float* __restrict__ Hs,
                                                 float* __restrict__ out) {
    int t = blockIdx.x;
    __shared__ float HA[256];
    __shared__ float HP[64];
    HA[threadIdx.x] = Hs[(size_t)t * 384 + 64 + threadIdx.x];
    if (threadIdx.x < 64) HP[threadIdx.x] = Hs[(size_t)t * 384 + 320 + threadIdx.x];
    __syncthreads();
    int rg = threadIdx.x >> 6;            // rows rg*4 .. rg*4+3
    int c0 = (threadIdx.x & 63) * 8;
    const bf16_t* srow = sb + (size_t)t * STATE;
    const bf16_t* lrow = Lout + (size_t)t * NDIM;
    float acc[4][8] = {};
    #pragma unroll
    for (int j = 0; j < 16; ++j) {
        bf16x8 v = *reinterpret_cast<const bf16x8*>(srow + j * CSZ + c0);
        float vf[8];
        #pragma unroll
        for (int x = 0; x < 8; ++x) vf[x] = (float)v[x];
        #pragma unroll
        for (int rr = 0; rr < 4; ++rr) {
            float h = HA[(rg * 4 + rr) * 16 + j];
            #pragma unroll
            for (int x = 0; x < 8; ++x) acc[rr][x] += h * vf[x];
        }
    }
    #pragma unroll
    for (int j = 0; j < 4; ++j) {
        bf16x8 v = *reinterpret_cast<const bf16x8*>(lrow + j * CSZ + c0);
        float vf[8];
        #pragma unroll
        for (int x = 0; x < 8; ++x) vf[x] = (float)v[x];
        #pragma unroll
        for (int rr = 0; rr < 4; ++rr) {
            float h = HP[(rg * 4 + rr) * 4 + j];
            #pragma unroll
            for (int x = 0; x < 8; ++x) acc[rr][x] += h * vf[x];
        }
    }
    #pragma unroll
    for (int rr = 0; rr < 4; ++rr) {
        float* orow = out + (size_t)t * STATE + (rg * 4 + rr) * CSZ + c0;
        f32x4 o0 = {acc[rr][0], acc[rr][1], acc[rr][2], acc[rr][3]};
        f32x4 o1 = {acc[rr][4], acc[rr][5], acc[rr][6], acc[rr][7]};
        *reinterpret_cast<f32x4*>(orow)     = o0;
        *reinterpret_cast<f32x4*>(orow + 4) = o1;
    }
}

// ---------------------------------------------------------------------------
extern "C" void kernel_launch(void* const* d_in, const int* in_sizes, int n_in,
                              void* d_out, int out_size, void* d_ws, size_t ws_size,
                              hipStream_t stream) {
    const float* s     = (const float*)d_in[0];
    const float* gamma = (const float*)d_in[1];
    const float* cmp   = (const float*)d_in[2];
    const float* b_pre = (const float*)d_in[3];
    const float* a_pre = (const float*)d_in[4];
    const float* tlpre = (const float*)d_in[5];
    const float* b_ali = (const float*)d_in[6];
    const float* a_ali = (const float*)d_in[7];
    const float* tlali = (const float*)d_in[8];
    const float* b_nxt = (const float*)d_in[9];
    const float* a_nxt = (const float*)d_in[10];
    const float* tlnxt = (const float*)d_in[11];
    const float* b_pst = (const float*)d_in[12];
    const float* a_pst = (const float*)d_in[13];
    const float* tlpst = (const float*)d_in[14];
    const float* W     = (const float*)d_in[15];
    float* out = (float*)d_out;
    const int T = in_sizes[0] / STATE;   // 8192

    char* ws = (char*)d_ws;
    size_t off = 0;
    auto take = [&](size_t bytes) {
        char* p = ws + off;
        off += (bytes + 255) & ~(size_t)255;
        return p;
    };
    bf16_t* sb   = (bf16_t*)take((size_t)T * STATE * 2);   // 128 MiB
    bf16_t* Cst  = (bf16_t*)take((size_t)DCOND * STATE * 2);
    bf16_t* TLt  = (bf16_t*)take((size_t)640 * DCOND * 2);
    bf16_t* Wt   = (bf16_t*)take((size_t)NDIM * NDIM * 2);
    float*  zsc  = (float*) take((size_t)T * 4);
    bf16_t* code = (bf16_t*)take((size_t)T * DCOND * 2);
    bf16_t* lrg  = (bf16_t*)take((size_t)T * 640 * 2);
    float*  Hsb  = (float*) take((size_t)T * 384 * 4);
    bf16_t* Lin  = (bf16_t*)take((size_t)T * NDIM * 2);
    bf16_t* Lout = (bf16_t*)take((size_t)T * NDIM * 2);

    // Split-K partial buffer (SK * T * 128 f32 = 32 MiB) aliases Lin:
    // it is fully consumed by reduce_code_sk before apply_pre writes Lin.
    float* Pcode = (float*)Lin;

    prep_wt<<<dim3(64, 64), dim3(32, 8), 0, stream>>>(W, Wt);
    prep_cs<<<dim3(4, 256), dim3(32, 8), 0, stream>>>(cmp, gamma, Cst);
    prep_tl<<<dim3(640), dim3(128), 0, stream>>>(tlpre, tlali, tlnxt, tlpst, TLt);
    norms_cast<<<dim3(T), dim3(256), 0, stream>>>(s, sb, zsc);
    // code_raw = s_bf16 @ Cs^T : M=T, N=128, K=8192 — split-K over 8 chunks
    gemm_code_sk<<<dim3(T / 128, SK), dim3(256), 0, stream>>>(sb, Cst, Pcode, T);
    reduce_code_sk<<<dim3(T * DCOND / 1024), dim3(256), 0, stream>>>(Pcode, code, T);
    // logits_raw = code_raw @ TL^T : M=T, N=640, K=128
    gemm_bt<<<dim3(T / 128, 5), dim3(256), 0, stream>>>(code, TLt, lrg, DCOND, 640);
    sinkhorn_k<<<dim3(T / 4), dim3(256), 0, stream>>>(lrg, zsc, b_pre, b_ali, b_nxt, b_pst,
                                                      a_pre, a_ali, a_nxt, a_pst, Hsb);
    apply_pre<<<dim3(T), dim3(256), 0, stream>>>(sb, Hsb, Lin);
    // layer_out = layer_in @ W : M=T, N=2048, K=2048
    gemm_bt<<<dim3(T / 128, 16), dim3(256), 0, stream>>>(Lin, Wt, Lout, NDIM, NDIM);
    write_out<<<dim3(T), dim3(256), 0, stream>>>(sb, Lout, Hsb, out);
}